// Round 9
// baseline (102.574 us; speedup 1.0000x reference)
//
#include <hip/hip_runtime.h>

#define CS   224
#define HH   1024
#define WW   1024
#define HW   (HH * WW)
#define RT   8               // rows per column tile
#define NTIL (HH / RT)       // 128
#define NCOLG 2              // 1024 cols / (256 threads * 2 floats)

// d_ws layout: I = 3*HW floats (12 MB), then colTab = 128*224 uint2 (229 KB).
// Tile sums S (1.5 MB) live in the tail of d_out (consumed before gather).

// ---- Pass 0: per-(n,j) column table -----------------------------------------
// acol|am<<15 in low 16 bits, bcol in high 16; .y = 1/nC as float bits.
__global__ __launch_bounds__(256) void make_tables(
    const int* __restrict__ sizesv, const int* __restrict__ oxv,
    uint2* __restrict__ colTab)
{
    int n = blockIdx.x;
    int j = threadIdx.x;
    if (j >= CS) return;
    int s  = sizesv[n];
    int ox = oxv[n];
    int lo = (j * s) / CS;
    int hi = ((j + 1) * s + (CS - 1)) / CS;
    int c0 = ox + lo, c1 = ox + hi;
    int nC = hi - lo;
    unsigned acol = (c0 > 0) ? ((unsigned)(c0 - 1) | 0x8000u) : 0u;
    unsigned bcol = (unsigned)(c1 - 1);
    uint2 e;
    e.x = acol | (bcol << 16);
    e.y = __float_as_uint(1.0f / (float)nC);
    colTab[n * CS + j] = e;
}

// ---- Pass 1: per-row inclusive cumsum into I (3072 blocks) ------------------
__global__ __launch_bounds__(256) void row_cumsum(
    const float* __restrict__ x, float* __restrict__ I)
{
    int row = blockIdx.x;                       // 0 .. 3*1024-1
    const float4* src = (const float4*)(x + (size_t)row * WW);
    float4*       dst = (float4*)(I + (size_t)row * WW);

    int t    = threadIdx.x;
    int lane = t & 63;
    int w    = t >> 6;

    float4 v = src[t];
    float s0 = v.x, s1 = s0 + v.y, s2 = s1 + v.z, s3 = s2 + v.w;
    float tsum = s3, sc = tsum;
    #pragma unroll
    for (int d = 1; d < 64; d <<= 1) {
        float o = __shfl_up(sc, d, 64);
        if (lane >= d) sc += o;
    }

    __shared__ float wsum[4];
    if (lane == 63) wsum[w] = sc;
    __syncthreads();
    float woff = 0.0f;
    #pragma unroll
    for (int k = 0; k < 4; ++k) woff += (k < w) ? wsum[k] : 0.0f;

    float ex = woff + sc - tsum;
    dst[t] = make_float4(ex + s0, ex + s1, ex + s2, ex + s3);
}

// ---- Pass 2: partial column cumsum per 8-row tile; tile sums -> S -----------
__global__ __launch_bounds__(256) void col_partial(
    float* __restrict__ I, float* __restrict__ Sf)
{
    int b    = blockIdx.x;
    int tile = b % NTIL;
    int cg   = (b / NTIL) % NCOLG;
    int ch   = b / (NTIL * NCOLG);
    int c2   = cg * 256 + threadIdx.x;

    float2* base = (float2*)(I + (size_t)ch * HW + (size_t)(tile * RT) * WW) + c2;
    float2* S2   = (float2*)Sf;

    float2 acc = make_float2(0.0f, 0.0f);
    #pragma unroll
    for (int r = 0; r < RT; ++r) {
        float2 v = base[(size_t)r * (WW / 2)];
        acc.x += v.x; acc.y += v.y;
        base[(size_t)r * (WW / 2)] = acc;
    }
    S2[(size_t)(ch * NTIL + tile) * (WW / 2) + c2] = acc;
}

// ---- Pass 3: inclusive scan of the 128 tile sums per column -----------------
// Thread = one column, serial over tiles; loads coalesced across threads.
__global__ __launch_bounds__(256) void scan_S(float* __restrict__ Sf)
{
    int c   = blockIdx.x * 256 + threadIdx.x;   // 0..3071
    int ch  = c >> 10;
    int col = c & (WW - 1);
    size_t base = (size_t)(ch * NTIL) * WW + col;
    float acc = 0.0f;
    for (int t = 0; t < NTIL; ++t) {
        size_t o = base + (size_t)t * WW;
        acc += Sf[o];
        Sf[o] = acc;
    }
}

// ---- Pass 4: add scanned tile offset (single load) to tiles 1..NTIL-1 -------
__global__ __launch_bounds__(256) void col_fixup(
    float* __restrict__ I, const float* __restrict__ Sf)
{
    int b    = blockIdx.x;
    int tile = b % (NTIL - 1) + 1;
    int cg   = (b / (NTIL - 1)) % NCOLG;
    int ch   = b / ((NTIL - 1) * NCOLG);
    int c2   = cg * 256 + threadIdx.x;

    const float2* S2 = (const float2*)Sf;
    float2 off = S2[(size_t)(ch * NTIL + tile - 1) * (WW / 2) + c2];

    float2* base = (float2*)(I + (size_t)ch * HW + (size_t)(tile * RT) * WW) + c2;
    #pragma unroll
    for (int r = 0; r < RT; ++r) {
        float2 v = base[(size_t)r * (WW / 2)];
        v.x += off.x; v.y += off.y;
        base[(size_t)r * (WW / 2)] = v;
    }
}

// ---- Pass 5: gather. Block = one output row; 4 direct SAT taps per lane. ----
// Row math is block-uniform (SALU + s_load); column math is one coalesced
// 8B table load per lane. rm is a wave-uniform branch.
__global__ __launch_bounds__(256) void cutouts_gather(
    const float* __restrict__ I,
    const uint2* __restrict__ colTab,
    const int*   __restrict__ sizesv,
    const int*   __restrict__ oyv,
    float*       __restrict__ out)
{
    int b   = blockIdx.x;              // ((ch*128)+n)*224 + i
    int i   = b % CS;
    int rem = b / CS;
    int n   = rem % 128;
    int ch  = rem / 128;               // slowest: working set = one 4MB plane

    int j = threadIdx.x;
    if (j >= CS) return;

    int s   = sizesv[n];               // block-uniform -> scalar
    int oy_ = oyv[n];

    int lo_i = (i * s) / CS;
    int nR   = ((i + 1) * s + (CS - 1)) / CS - lo_i;
    int r0   = oy_ + lo_i;
    int r1m  = r0 + nR - 1;
    bool rm  = (r0 > 0);
    int r0m  = rm ? (r0 - 1) : 0;

    const float* Rhi = I + (size_t)ch * HW + (size_t)r1m * WW;
    const float* Rlo = I + (size_t)ch * HW + (size_t)r0m * WW;

    uint2 ci = colTab[n * CS + j];     // coalesced 8B load
    int   acol  = (int)(ci.x & 0x7fffu);
    int   bcol  = (int)(ci.x >> 16);
    bool  am    = (ci.x & 0x8000u) != 0;
    float rcpNC = __uint_as_float(ci.y);

    float t11 = Rhi[bcol];
    float t10 = Rhi[acol];
    float sum;
    if (rm) {                          // wave-uniform branch
        float t01 = Rlo[bcol];
        float t00 = Rlo[acol];
        float hiD = t11 - t01;
        float loD = t10 - t00;
        sum = hiD - (am ? loD : 0.0f);
    } else {
        sum = t11 - (am ? t10 : 0.0f);
    }

    float rcpNR = __builtin_amdgcn_rcpf((float)nR);
    out[((size_t)((n * 3 + ch) * CS) + i) * CS + j] = sum * (rcpNC * rcpNR);
}

extern "C" void kernel_launch(void* const* d_in, const int* in_sizes, int n_in,
                              void* d_out, int out_size, void* d_ws, size_t ws_size,
                              hipStream_t stream) {
    const float* x     = (const float*)d_in[0];
    const int*   sizes = (const int*)d_in[1];
    const int*   oy    = (const int*)d_in[2];
    const int*   ox    = (const int*)d_in[3];
    float*       out   = (float*)d_out;
    float*       I     = (float*)d_ws;                       // 12 MB
    uint2*       colTab = (uint2*)((char*)d_ws + (size_t)3 * HW * 4); // +229 KB

    // Tile sums S (3*128*1024 floats = 1.5 MB) in the tail of d_out;
    // fully consumed by col_fixup before the gather overwrites d_out.
    float* S = out + (out_size - 3 * NTIL * WW);

    make_tables<<<128, 256, 0, stream>>>(sizes, ox, colTab);
    row_cumsum<<<3 * HH, 256, 0, stream>>>(x, I);
    col_partial<<<3 * NCOLG * NTIL, 256, 0, stream>>>(I, S);
    scan_S<<<12, 256, 0, stream>>>(S);
    col_fixup<<<3 * NCOLG * (NTIL - 1), 256, 0, stream>>>(I, S);

    int blocks = 3 * 128 * CS;                               // 86016
    cutouts_gather<<<blocks, 256, 0, stream>>>(I, colTab, sizes, oy, out);
}

// Round 10
// 76.469 us; speedup vs baseline: 1.3414x; 1.3414x over previous
//
#include <hip/hip_runtime.h>

#define CS   224
#define HH   1024
#define WW   1024
#define HW   (HH * WW)
#define RT   16              // rows per column tile
#define NTIL (HH / RT)       // 64
#define NCOLG 2              // 1024 cols / (256 threads * 2 floats)
#define ROWS 4               // output rows per gather block

// ---- Pass 1: per-row inclusive cumsum into I (3072 blocks) -----------------
__global__ __launch_bounds__(256) void row_cumsum(
    const float* __restrict__ x, float* __restrict__ I)
{
    int row = blockIdx.x;                       // 0 .. 3*1024-1
    const float4* src = (const float4*)(x + (size_t)row * WW);
    float4*       dst = (float4*)(I + (size_t)row * WW);

    int t    = threadIdx.x;
    int lane = t & 63;
    int w    = t >> 6;

    float4 v = src[t];
    float s0 = v.x, s1 = s0 + v.y, s2 = s1 + v.z, s3 = s2 + v.w;
    float tsum = s3, sc = tsum;
    #pragma unroll
    for (int d = 1; d < 64; d <<= 1) {
        float o = __shfl_up(sc, d, 64);
        if (lane >= d) sc += o;
    }

    __shared__ float wsum[4];
    if (lane == 63) wsum[w] = sc;
    __syncthreads();
    float woff = 0.0f;
    #pragma unroll
    for (int k = 0; k < 4; ++k) woff += (k < w) ? wsum[k] : 0.0f;

    float ex = woff + sc - tsum;
    dst[t] = make_float4(ex + s0, ex + s1, ex + s2, ex + s3);
}

// ---- Pass 2: partial column cumsum per 16-row tile; tile sums -> S ---------
__global__ __launch_bounds__(256) void col_partial(
    float* __restrict__ I, float* __restrict__ Sf)
{
    int b    = blockIdx.x;
    int tile = b % NTIL;
    int cg   = (b / NTIL) % NCOLG;
    int ch   = b / (NTIL * NCOLG);
    int c2   = cg * 256 + threadIdx.x;

    float2* base = (float2*)(I + (size_t)ch * HW + (size_t)(tile * RT) * WW) + c2;
    float2* S2   = (float2*)Sf;

    float2 acc = make_float2(0.0f, 0.0f);
    #pragma unroll
    for (int r = 0; r < RT; ++r) {
        float2 v = base[(size_t)r * (WW / 2)];
        acc.x += v.x; acc.y += v.y;
        base[(size_t)r * (WW / 2)] = acc;
    }
    S2[(size_t)(ch * NTIL + tile) * (WW / 2) + c2] = acc;
}

// ---- Pass 3: inclusive scan of the 64 tile sums per column (wave/column) ---
__global__ __launch_bounds__(256) void scan_S(float* __restrict__ Sf)
{
    int gw   = (blockIdx.x * 256 + threadIdx.x) >> 6;   // global wave id
    int lane = threadIdx.x & 63;
    int c    = gw % WW;
    int ch   = gw / WW;                                 // 0..2

    size_t idx = ((size_t)(ch * NTIL + lane)) * WW + c;
    float v = Sf[idx];
    #pragma unroll
    for (int d = 1; d < 64; d <<= 1) {
        float o = __shfl_up(v, d, 64);
        if (lane >= d) v += o;
    }
    Sf[idx] = v;
}

// ---- Pass 4: add scanned tile offsets (tiles 1..NTIL-1) --------------------
__global__ __launch_bounds__(256) void col_fixup(
    float* __restrict__ I, const float* __restrict__ Sf)
{
    int b    = blockIdx.x;
    int tile = b % (NTIL - 1) + 1;
    int cg   = (b / (NTIL - 1)) % NCOLG;
    int ch   = b / ((NTIL - 1) * NCOLG);
    int c2   = cg * 256 + threadIdx.x;

    const float2* S2 = (const float2*)Sf;
    float2 off = S2[(size_t)(ch * NTIL + tile - 1) * (WW / 2) + c2];

    float2* base = (float2*)(I + (size_t)ch * HW + (size_t)(tile * RT) * WW) + c2;
    #pragma unroll
    for (int r = 0; r < RT; ++r) {
        float2 v = base[(size_t)r * (WW / 2)];
        v.x += off.x; v.y += off.y;
        base[(size_t)r * (WW / 2)] = v;
    }
}

// ---- Pass 5: gather. Block = 4 output rows of one (n,ch); lane = column. ---
// Column math computed once per lane, reused for all 4 rows. Row math is
// block-uniform (SALU). 16 independent taps in flight per lane.
__global__ __launch_bounds__(256) void cutouts_gather(
    const float* __restrict__ I,
    const int*   __restrict__ sizesv,
    const int*   __restrict__ oyv,
    const int*   __restrict__ oxv,
    float*       __restrict__ out)
{
    int b   = blockIdx.x;              // ((ch*128)+n)*56 + rg
    int rg  = b % (CS / ROWS);
    int rem = b / (CS / ROWS);
    int n   = rem % 128;
    int ch  = rem / 128;               // slowest: working set = one 4MB plane

    int j = threadIdx.x;
    if (j >= CS) return;

    int s   = sizesv[n];               // block-uniform -> scalar
    int oy_ = oyv[n];
    int ox_ = oxv[n];

    // per-lane column math, once for all ROWS rows
    int lo_j = (j * s) / CS;
    int hi_j = ((j + 1) * s + (CS - 1)) / CS;
    int c0   = ox_ + lo_j;
    int bcol = ox_ + hi_j - 1;                  // >= 0 always
    bool am  = (c0 > 0);
    int acol = am ? (c0 - 1) : 0;
    float rcpC = __builtin_amdgcn_rcpf((float)(hi_j - lo_j));

    const float* Ic = I + (size_t)ch * HW;

    #pragma unroll
    for (int rr = 0; rr < ROWS; ++rr) {
        int i    = rg * ROWS + rr;
        int lo_i = (i * s) / CS;
        int nR   = ((i + 1) * s + (CS - 1)) / CS - lo_i;
        int r0   = oy_ + lo_i;
        int r1m  = r0 + nR - 1;
        bool rm  = (r0 > 0);
        int r0m  = rm ? (r0 - 1) : 0;

        const float* Rhi = Ic + (size_t)r1m * WW;
        const float* Rlo = Ic + (size_t)r0m * WW;

        float t11 = Rhi[bcol];
        float t10 = Rhi[acol];
        float t01 = Rlo[bcol];
        float t00 = Rlo[acol];

        float sum = t11
                  - (am ? t10 : 0.0f)
                  - (rm ? t01 : 0.0f)
                  + ((am && rm) ? t00 : 0.0f);

        float rcpR = __builtin_amdgcn_rcpf((float)nR);
        out[((size_t)((n * 3 + ch) * CS) + i) * CS + j] = sum * (rcpC * rcpR);
    }
}

extern "C" void kernel_launch(void* const* d_in, const int* in_sizes, int n_in,
                              void* d_out, int out_size, void* d_ws, size_t ws_size,
                              hipStream_t stream) {
    const float* x     = (const float*)d_in[0];
    const int*   sizes = (const int*)d_in[1];
    const int*   oy    = (const int*)d_in[2];
    const int*   ox    = (const int*)d_in[3];
    float*       out   = (float*)d_out;
    float*       I     = (float*)d_ws;               // 12 MB

    // Tile sums S (3*64*1024 floats = 768 KB) in the tail of d_out;
    // fully consumed before the gather overwrites all of d_out.
    float* S = out + (out_size - 3 * NTIL * WW);

    row_cumsum<<<3 * HH, 256, 0, stream>>>(x, I);
    col_partial<<<3 * NCOLG * NTIL, 256, 0, stream>>>(I, S);
    scan_S<<<(3 * WW) / 4, 256, 0, stream>>>(S);       // 768 blocks
    col_fixup<<<3 * NCOLG * (NTIL - 1), 256, 0, stream>>>(I, S);

    int blocks = 3 * 128 * (CS / ROWS);               // 21504
    cutouts_gather<<<blocks, 256, 0, stream>>>(I, sizes, oy, ox, out);
}

// Round 11
// 69.869 us; speedup vs baseline: 1.4681x; 1.0945x over previous
//
#include <hip/hip_runtime.h>

#define CS   224
#define HH   1024
#define WW   1024
#define HW   (HH * WW)
#define RT   16              // rows per column tile
#define NTIL (HH / RT)       // 64
#define NCOLG 2              // 1024 cols / (256 threads * 2 floats)
#define ROWS 4               // output rows per gather block

// ---- Pass 1: per-row inclusive cumsum into I (3072 blocks) -----------------
__global__ __launch_bounds__(256) void row_cumsum(
    const float* __restrict__ x, float* __restrict__ I)
{
    int row = blockIdx.x;                       // 0 .. 3*1024-1
    const float4* src = (const float4*)(x + (size_t)row * WW);
    float4*       dst = (float4*)(I + (size_t)row * WW);

    int t    = threadIdx.x;
    int lane = t & 63;
    int w    = t >> 6;

    float4 v = src[t];
    float s0 = v.x, s1 = s0 + v.y, s2 = s1 + v.z, s3 = s2 + v.w;
    float tsum = s3, sc = tsum;
    #pragma unroll
    for (int d = 1; d < 64; d <<= 1) {
        float o = __shfl_up(sc, d, 64);
        if (lane >= d) sc += o;
    }

    __shared__ float wsum[4];
    if (lane == 63) wsum[w] = sc;
    __syncthreads();
    float woff = 0.0f;
    #pragma unroll
    for (int k = 0; k < 4; ++k) woff += (k < w) ? wsum[k] : 0.0f;

    float ex = woff + sc - tsum;
    dst[t] = make_float4(ex + s0, ex + s1, ex + s2, ex + s3);
}

// ---- Pass 2: read-only tile column sums -> S -------------------------------
__global__ __launch_bounds__(256) void col_sum(
    const float* __restrict__ I, float* __restrict__ Sf)
{
    int b    = blockIdx.x;
    int tile = b % NTIL;
    int cg   = (b / NTIL) % NCOLG;
    int ch   = b / (NTIL * NCOLG);
    int c2   = cg * 256 + threadIdx.x;

    const float2* base = (const float2*)(I + (size_t)ch * HW
                                           + (size_t)(tile * RT) * WW) + c2;
    float2 acc = make_float2(0.0f, 0.0f);
    #pragma unroll
    for (int r = 0; r < RT; ++r) {
        float2 v = base[(size_t)r * (WW / 2)];
        acc.x += v.x; acc.y += v.y;
    }
    ((float2*)Sf)[(size_t)(ch * NTIL + tile) * (WW / 2) + c2] = acc;
}

// ---- Pass 3: inclusive scan of the 64 tile sums per column (wave/column) ---
__global__ __launch_bounds__(256) void scan_S(float* __restrict__ Sf)
{
    int gw   = (blockIdx.x * 256 + threadIdx.x) >> 6;   // global wave id
    int lane = threadIdx.x & 63;
    int c    = gw % WW;
    int ch   = gw / WW;                                 // 0..2

    size_t idx = ((size_t)(ch * NTIL + lane)) * WW + c;
    float v = Sf[idx];
    #pragma unroll
    for (int d = 1; d < 64; d <<= 1) {
        float o = __shfl_up(v, d, 64);
        if (lane >= d) v += o;
    }
    Sf[idx] = v;
}

// ---- Pass 4: fused within-tile cumsum + scanned offset (one I pass) --------
__global__ __launch_bounds__(256) void col_apply(
    float* __restrict__ I, const float* __restrict__ Sf)
{
    int b    = blockIdx.x;
    int tile = b % NTIL;
    int cg   = (b / NTIL) % NCOLG;
    int ch   = b / (NTIL * NCOLG);
    int c2   = cg * 256 + threadIdx.x;

    float2 acc = make_float2(0.0f, 0.0f);
    if (tile > 0)
        acc = ((const float2*)Sf)[(size_t)(ch * NTIL + tile - 1) * (WW / 2) + c2];

    float2* base = (float2*)(I + (size_t)ch * HW + (size_t)(tile * RT) * WW) + c2;
    #pragma unroll
    for (int r = 0; r < RT; ++r) {
        float2 v = base[(size_t)r * (WW / 2)];
        acc.x += v.x; acc.y += v.y;
        base[(size_t)r * (WW / 2)] = acc;
    }
}

// ---- Pass 5: gather. Block = 4 output rows of one (n,ch); lane = column. ---
// Explicit load/consume split: all 16 tap loads issue before any consumer
// (16-wide MLP per lane). Column math computed once per lane; row math is
// block-uniform SALU.
__global__ __launch_bounds__(256) void cutouts_gather(
    const float* __restrict__ I,
    const int*   __restrict__ sizesv,
    const int*   __restrict__ oyv,
    const int*   __restrict__ oxv,
    float*       __restrict__ out)
{
    int b   = blockIdx.x;              // ((ch*128)+n)*56 + rg
    int rg  = b % (CS / ROWS);
    int rem = b / (CS / ROWS);
    int n   = rem % 128;
    int ch  = rem / 128;               // slowest: working set = one 4MB plane

    int j = threadIdx.x;
    if (j >= CS) return;

    int s   = sizesv[n];               // block-uniform -> scalar
    int oy_ = oyv[n];
    int ox_ = oxv[n];

    // per-lane column math, once for all ROWS rows
    int lo_j = (j * s) / CS;
    int hi_j = ((j + 1) * s + (CS - 1)) / CS;
    int c0   = ox_ + lo_j;
    int bcol = ox_ + hi_j - 1;                  // >= 0 always
    bool am  = (c0 > 0);
    int acol = am ? (c0 - 1) : 0;
    float rcpC = __builtin_amdgcn_rcpf((float)(hi_j - lo_j));

    const float* Ic = I + (size_t)ch * HW;

    // (a) row setup: pointers + masks (block-uniform values)
    const float* rowHi[ROWS];
    const float* rowLo[ROWS];
    bool  rmv[ROWS];
    float rcpA[ROWS];
    #pragma unroll
    for (int rr = 0; rr < ROWS; ++rr) {
        int i    = rg * ROWS + rr;
        int lo_i = (i * s) / CS;
        int nR   = ((i + 1) * s + (CS - 1)) / CS - lo_i;
        int r0   = oy_ + lo_i;
        int r1m  = r0 + nR - 1;
        bool rm  = (r0 > 0);
        int r0m  = rm ? (r0 - 1) : 0;
        rowHi[rr] = Ic + (size_t)r1m * WW;
        rowLo[rr] = Ic + (size_t)r0m * WW;
        rmv[rr]   = rm;
        rcpA[rr]  = rcpC * __builtin_amdgcn_rcpf((float)nR);
    }

    // (b) issue ALL 16 loads back-to-back (no consumer in between)
    float vhb[ROWS], vha[ROWS], vlb[ROWS], vla[ROWS];
    #pragma unroll
    for (int rr = 0; rr < ROWS; ++rr) {
        vhb[rr] = rowHi[rr][bcol];
        vha[rr] = rowHi[rr][acol];
        vlb[rr] = rowLo[rr][bcol];
        vla[rr] = rowLo[rr][acol];
    }

    // (c) combine + store
    #pragma unroll
    for (int rr = 0; rr < ROWS; ++rr) {
        int i = rg * ROWS + rr;
        float sum = vhb[rr]
                  - (am ? vha[rr] : 0.0f)
                  - (rmv[rr] ? vlb[rr] : 0.0f)
                  + ((am && rmv[rr]) ? vla[rr] : 0.0f);
        out[((size_t)((n * 3 + ch) * CS) + i) * CS + j] = sum * rcpA[rr];
    }
}

extern "C" void kernel_launch(void* const* d_in, const int* in_sizes, int n_in,
                              void* d_out, int out_size, void* d_ws, size_t ws_size,
                              hipStream_t stream) {
    const float* x     = (const float*)d_in[0];
    const int*   sizes = (const int*)d_in[1];
    const int*   oy    = (const int*)d_in[2];
    const int*   ox    = (const int*)d_in[3];
    float*       out   = (float*)d_out;
    float*       I     = (float*)d_ws;               // 12 MB

    // Tile sums S (3*64*1024 floats = 768 KB) in the tail of d_out;
    // fully consumed by col_apply before the gather overwrites all of d_out.
    float* S = out + (out_size - 3 * NTIL * WW);

    row_cumsum<<<3 * HH, 256, 0, stream>>>(x, I);
    col_sum<<<3 * NCOLG * NTIL, 256, 0, stream>>>(I, S);
    scan_S<<<(3 * WW) / 4, 256, 0, stream>>>(S);       // 768 blocks
    col_apply<<<3 * NCOLG * NTIL, 256, 0, stream>>>(I, S);

    int blocks = 3 * 128 * (CS / ROWS);               // 21504
    cutouts_gather<<<blocks, 256, 0, stream>>>(I, sizes, oy, ox, out);
}